// Round 16
// baseline (89.557 us; speedup 1.0000x reference)
//
#include <hip/hip_runtime.h>
#include <math.h>

constexpr int B = 1024;
constexpr int D = 128;
constexpr int Q = 65536;
constexpr int NPART = 1024;      // 512 N-tiles x 2 wave-cols
#define TEMP_INV 5.0f
#define EPS 1e-12f

typedef __bf16 bf16x8 __attribute__((ext_vector_type(8)));
typedef float  f32x4  __attribute__((ext_vector_type(4)));

__device__ __forceinline__ float wave_reduce_sum(float v) {
    #pragma unroll
    for (int off = 32; off > 0; off >>= 1) v += __shfl_xor(v, off);
    return v;
}

__device__ __forceinline__ unsigned short f2bf(float x) {
    unsigned int u = __float_as_uint(x);
    unsigned int r = (u + 0x7FFFu + ((u >> 16) & 1u)) >> 16;   // RNE
    return (unsigned short)r;
}

// --- K1: fused preprocessing (R15-verbatim) -------------------------------
// blocks [0, 8192):  l2-normalize 8 queue rows -> bf16 qb
// blocks [8192, 8704): normalize 2 g1/g2 rows -> qnb bf16, pos_sim
__global__ __launch_bounds__(256) void k_prep(const float* __restrict__ g1,
                                              const float* __restrict__ g2,
                                              const float* __restrict__ queue,
                                              unsigned short* __restrict__ qnb,
                                              unsigned short* __restrict__ qb,
                                              float* __restrict__ out_pos,
                                              float* __restrict__ ws_pos) {
    if (blockIdx.x < Q / 8) {
        int half = threadIdx.x >> 5;        // 0..7
        int l    = threadIdx.x & 31;
        int row  = blockIdx.x * 8 + half;
        const f32x4* src = (const f32x4*)(queue + (size_t)row * D);
        f32x4 v = __builtin_nontemporal_load(&src[l]);
        float ss = v.x * v.x + v.y * v.y + v.z * v.z + v.w * v.w;
        #pragma unroll
        for (int off = 16; off > 0; off >>= 1) ss += __shfl_xor(ss, off);
        float inv = 1.0f / fmaxf(sqrtf(ss), EPS);
        uint2 o;
        o.x = (unsigned int)f2bf(v.x * inv) | ((unsigned int)f2bf(v.y * inv) << 16);
        o.y = (unsigned int)f2bf(v.z * inv) | ((unsigned int)f2bf(v.w * inv) << 16);
        ((uint2*)(qb + (size_t)row * D))[l] = o;
    } else {
        int idx = blockIdx.x - Q / 8;
        int w2 = threadIdx.x >> 7;          // row within block (0..1)
        int tt = threadIdx.x & 127;         // 0..127 feature dim
        int b  = idx * 2 + w2;
        int w  = tt >> 6, lane = tt & 63;
        float x = g1[b * D + tt];
        float y = g2[b * D + tt];
        __shared__ float sx[2][2], sy[2][2], sp[2][2];
        float xs = wave_reduce_sum(x * x);
        float ys = wave_reduce_sum(y * y);
        if (lane == 0) { sx[w2][w] = xs; sy[w2][w] = ys; }
        __syncthreads();
        float ix = 1.0f / fmaxf(sqrtf(sx[w2][0] + sx[w2][1]), EPS);
        float iy = 1.0f / fmaxf(sqrtf(sy[w2][0] + sy[w2][1]), EPS);
        float qv = x * ix;
        float kv = y * iy;
        qnb[b * D + tt] = f2bf(qv);
        float p = wave_reduce_sum(qv * kv);
        if (lane == 0) sp[w2][w] = p;
        __syncthreads();
        if (tt == 0) {
            float pos = (sp[w2][0] + sp[w2][1]) * TEMP_INV;
            out_pos[b] = pos;
            ws_pos[b]  = pos;
        }
    }
}

// --- K2: MFMA GEMM + fused fixed-ref partial sumexp -----------------------
// 256M x 128N tile, 512 threads, 4x2 waves (each wave 64x64) -> 2 blocks/CU
// (phase overlap: one block's stores hide the other's staging/MFMA).
// Swapped-operand MFMA -> register-direct float4 stores, no post-K barriers.
// XCD-aware swizzle: 4 by-blocks of one bx consecutive on the SAME XCD.
__global__ __launch_bounds__(512) void k_gemm_mfma(const unsigned short* __restrict__ qnb,
                                                   const unsigned short* __restrict__ qb,
                                                   float* __restrict__ neg,
                                                   float* __restrict__ psum) {
    __shared__ unsigned short As[256][72];   // 36.9KB (+8 pad)
    __shared__ unsigned short Bs[128][72];   // 18.4KB ; total 55.3KB -> 2 blocks/CU
    const int t  = threadIdx.x;
    const int blk = blockIdx.x;
    const int xcd = blk & 7;       // dispatch XCD (round-robin)
    const int i   = blk >> 3;      // 0..255 local index within XCD
    const int bx  = xcd * 64 + (i >> 2);   // 0..511 over Q, contiguous per XCD
    const int by  = i & 3;                  // 0..3 over B (fast -> qb reuse in-XCD)
    const int R0 = by * 256, C0 = bx * 128;
    const int wid = t >> 6, lane = t & 63;
    const int wr = wid >> 1, wc = wid & 1;    // 4x2 wave grid
    const int lg = lane >> 4, lc = lane & 15;

    f32x4 acc[4][4];               // [n][m] (transposed output)
    #pragma unroll
    for (int n = 0; n < 4; ++n)
        #pragma unroll
        for (int m = 0; m < 4; ++m)
            #pragma unroll
            for (int r = 0; r < 4; ++r) acc[n][m][r] = 0.0f;

    #pragma unroll
    for (int s = 0; s < 2; ++s) {
        if (s) __syncthreads();
        const int ks = s * 64;
        #pragma unroll
        for (int p = 0; p < 4; ++p) {       // A: 256 rows
            int c   = t + 512 * p;
            int row = c >> 3;               // 0..255
            int off = (c & 7) * 8;          // bf16 col, 0..56
            uint4 va = *(const uint4*)(qnb + (size_t)(R0 + row) * D + ks + off);
            *(uint4*)&As[row][off] = va;
        }
        #pragma unroll
        for (int p = 0; p < 2; ++p) {       // B: 128 rows
            int c   = t + 512 * p;
            int row = c >> 3;               // 0..127
            int off = (c & 7) * 8;
            uint4 vb = *(const uint4*)(qb + (size_t)(C0 + row) * D + ks + off);
            *(uint4*)&Bs[row][off] = vb;
        }
        __syncthreads();
        #pragma unroll
        for (int kk = 0; kk < 64; kk += 32) {
            int ko = kk + lg * 8;
            bf16x8 a[4], b[4];
            #pragma unroll
            for (int m = 0; m < 4; ++m)
                a[m] = *(const bf16x8*)&As[wr * 64 + m * 16 + lc][ko];
            #pragma unroll
            for (int n = 0; n < 4; ++n)
                b[n] = *(const bf16x8*)&Bs[wc * 64 + n * 16 + lc][ko];
            #pragma unroll
            for (int n = 0; n < 4; ++n)
                #pragma unroll
                for (int m = 0; m < 4; ++m)
                    acc[n][m] = __builtin_amdgcn_mfma_f32_16x16x32_bf16(b[n], a[m], acc[n][m], 0, 0, 0);
        }
    }

    // ---- epilogue: direct register->global float4 stores + fused fixed-ref
    //      sumexp (logits in [-5,5] -> M=5). No barriers, no LDS.
    const int slot = bx * 2 + wc;
    #pragma unroll
    for (int m = 0; m < 4; ++m) {
        const size_t rowBase = (size_t)(R0 + wr * 64 + m * 16 + lc) * Q + C0 + wc * 64;
        float e = 0.0f;
        #pragma unroll
        for (int n = 0; n < 4; ++n) {
            float v0 = acc[n][m][0] * TEMP_INV;
            float v1 = acc[n][m][1] * TEMP_INV;
            float v2 = acc[n][m][2] * TEMP_INV;
            float v3 = acc[n][m][3] * TEMP_INV;
            float4 o = make_float4(v0, v1, v2, v3);
            *(float4*)(neg + rowBase + n * 16 + lg * 4) = o;
            e += __expf(v0 - 5.0f) + __expf(v1 - 5.0f) +
                 __expf(v2 - 5.0f) + __expf(v3 - 5.0f);
        }
        e += __shfl_xor(e, 16);
        e += __shfl_xor(e, 32);
        if (lg == 0) {
            int gr = R0 + wr * 64 + m * 16 + lc;
            psum[(size_t)gr * NPART + slot] = e;
        }
    }
}

// --- K3: reduce 1024 partial sums per row + pos -> loss_b -----------------
__global__ __launch_bounds__(256) void k_reduce_lse(const float* __restrict__ psum,
                                                    const float* __restrict__ ws_pos,
                                                    float* __restrict__ loss_b) {
    int r = blockIdx.x;
    const float4* pr = (const float4*)(psum + (size_t)r * NPART);
    float4 v = pr[threadIdx.x];        // 256 threads x float4 = 1024 slots
    float s = v.x + v.y + v.z + v.w;
    s = wave_reduce_sum(s);
    __shared__ float sw[4];
    int w = threadIdx.x >> 6, lane = threadIdx.x & 63;
    if (lane == 0) sw[w] = s;
    __syncthreads();
    if (threadIdx.x == 0) {
        float S = sw[0] + sw[1] + sw[2] + sw[3];
        float pos = ws_pos[r];
        S += __expf(pos - 5.0f);
        loss_b[r] = (logf(S) + 5.0f) - pos;   // lse - pos
    }
}

// --- K4: mean of loss_b -> out[0] -----------------------------------------
__global__ void k_loss_mean(const float* __restrict__ loss_b, float* __restrict__ out) {
    float s = 0.0f;
    for (int i = threadIdx.x; i < B; i += 256) s += loss_b[i];
    s = wave_reduce_sum(s);
    __shared__ float sw[4];
    int w = threadIdx.x >> 6, lane = threadIdx.x & 63;
    if (lane == 0) sw[w] = s;
    __syncthreads();
    if (threadIdx.x == 0) out[0] = (sw[0] + sw[1] + sw[2] + sw[3]) / (float)B;
}

extern "C" void kernel_launch(void* const* d_in, const int* in_sizes, int n_in,
                              void* d_out, int out_size, void* d_ws, size_t ws_size,
                              hipStream_t stream) {
    const float* g1    = (const float*)d_in[0];
    const float* g2    = (const float*)d_in[1];
    const float* queue = (const float*)d_in[2];
    float* out = (float*)d_out;

    float* out_pos = out + 1;          // pos_sim [B]
    float* neg     = out + 1 + B;      // neg_sim [B][Q]

    // ws layout: qnb bf16[B*D] | qb bf16[Q*D] | psum f32[B*NPART]
    //            | ws_pos f32[B] | loss_b f32[B]
    unsigned short* qnb = (unsigned short*)d_ws;
    unsigned short* qb  = qnb + (size_t)B * D;
    float* psum   = (float*)(qb + (size_t)Q * D);
    float* ws_pos = psum + (size_t)B * NPART;
    float* loss_b = ws_pos + B;

    k_prep<<<Q / 8 + B / 2, 256, 0, stream>>>(g1, g2, queue, qnb, qb, out_pos, ws_pos);
    k_gemm_mfma<<<(Q / 128) * (B / 256), 512, 0, stream>>>(qnb, qb, neg, psum);
    k_reduce_lse<<<B, 256, 0, stream>>>(psum, ws_pos, loss_b);
    k_loss_mean<<<1, 256, 0, stream>>>(loss_b, out);
}

// Round 17
// 88.994 us; speedup vs baseline: 1.0063x; 1.0063x over previous
//
#include <hip/hip_runtime.h>
#include <math.h>

constexpr int B = 1024;
constexpr int D = 128;
constexpr int Q = 65536;
constexpr int NPART = 1024;      // 256 N-tiles x 4 wave-cols
#define TEMP_INV 5.0f
#define EPS 1e-12f

typedef __bf16 bf16x8 __attribute__((ext_vector_type(8)));
typedef float  f32x4  __attribute__((ext_vector_type(4)));

__device__ __forceinline__ float wave_reduce_sum(float v) {
    #pragma unroll
    for (int off = 32; off > 0; off >>= 1) v += __shfl_xor(v, off);
    return v;
}

__device__ __forceinline__ unsigned short f2bf(float x) {
    unsigned int u = __float_as_uint(x);
    unsigned int r = (u + 0x7FFFu + ((u >> 16) & 1u)) >> 16;   // RNE
    return (unsigned short)r;
}

// --- K1: fused preprocessing ----------------------------------------------
// blocks [0, 8192):  l2-normalize 8 queue rows -> bf16 qb
// blocks [8192, 8704): normalize 2 g1/g2 rows -> qnb bf16, pos_sim
__global__ __launch_bounds__(256) void k_prep(const float* __restrict__ g1,
                                              const float* __restrict__ g2,
                                              const float* __restrict__ queue,
                                              unsigned short* __restrict__ qnb,
                                              unsigned short* __restrict__ qb,
                                              float* __restrict__ out_pos,
                                              float* __restrict__ ws_pos) {
    if (blockIdx.x < Q / 8) {
        int half = threadIdx.x >> 5;        // 0..7
        int l    = threadIdx.x & 31;
        int row  = blockIdx.x * 8 + half;
        const f32x4* src = (const f32x4*)(queue + (size_t)row * D);
        f32x4 v = __builtin_nontemporal_load(&src[l]);
        float ss = v.x * v.x + v.y * v.y + v.z * v.z + v.w * v.w;
        #pragma unroll
        for (int off = 16; off > 0; off >>= 1) ss += __shfl_xor(ss, off);
        float inv = 1.0f / fmaxf(sqrtf(ss), EPS);
        uint2 o;
        o.x = (unsigned int)f2bf(v.x * inv) | ((unsigned int)f2bf(v.y * inv) << 16);
        o.y = (unsigned int)f2bf(v.z * inv) | ((unsigned int)f2bf(v.w * inv) << 16);
        ((uint2*)(qb + (size_t)row * D))[l] = o;
    } else {
        int idx = blockIdx.x - Q / 8;
        int w2 = threadIdx.x >> 7;          // row within block (0..1)
        int tt = threadIdx.x & 127;         // 0..127 feature dim
        int b  = idx * 2 + w2;
        int w  = tt >> 6, lane = tt & 63;
        float x = g1[b * D + tt];
        float y = g2[b * D + tt];
        __shared__ float sx[2][2], sy[2][2], sp[2][2];
        float xs = wave_reduce_sum(x * x);
        float ys = wave_reduce_sum(y * y);
        if (lane == 0) { sx[w2][w] = xs; sy[w2][w] = ys; }
        __syncthreads();
        float ix = 1.0f / fmaxf(sqrtf(sx[w2][0] + sx[w2][1]), EPS);
        float iy = 1.0f / fmaxf(sqrtf(sy[w2][0] + sy[w2][1]), EPS);
        float qv = x * ix;
        float kv = y * iy;
        qnb[b * D + tt] = f2bf(qv);
        float p = wave_reduce_sum(qv * kv);
        if (lane == 0) sp[w2][w] = p;
        __syncthreads();
        if (tt == 0) {
            float pos = (sp[w2][0] + sp[w2][1]) * TEMP_INV;
            out_pos[b] = pos;
            ws_pos[b]  = pos;
        }
    }
}

// --- K2: MFMA GEMM + fused fixed-ref partial sumexp -----------------------
// 256x256 tile, 1024 threads, 4x4 waves; swapped-operand MFMA ->
// register-direct float4 stores, no post-K barriers.
// XCD-aware swizzle: dispatch round-robins XCD = blk&7; give each XCD a
// contiguous bx range and keep the 4 by-blocks of one bx consecutive on
// the SAME XCD -> qb tile: 1 L3 fetch + 3 same-XCD L2 hits.
__global__ __launch_bounds__(1024) void k_gemm_mfma(const unsigned short* __restrict__ qnb,
                                                    const unsigned short* __restrict__ qb,
                                                    float* __restrict__ neg,
                                                    float* __restrict__ psum) {
    __shared__ unsigned short SM[2][256][72];   // As=SM[0], Bs=SM[1]; 73.7KB
    const int t  = threadIdx.x;
    const int blk = blockIdx.x;
    const int xcd = blk & 7;       // dispatch XCD (round-robin)
    const int i   = blk >> 3;      // 0..127 local index within XCD
    const int bx  = xcd * 32 + (i >> 2);   // 0..255 over Q, contiguous per XCD
    const int by  = i & 3;                  // 0..3 over B (fast -> qb reuse in-XCD)
    const int R0 = by * 256, C0 = bx * 256;
    const int wid = t >> 6, lane = t & 63;
    const int wr = wid >> 2, wc = wid & 3;    // 4x4 wave grid
    const int lg = lane >> 4, lc = lane & 15;

    f32x4 acc[4][4];               // [n][m] (transposed output)
    #pragma unroll
    for (int n = 0; n < 4; ++n)
        #pragma unroll
        for (int m = 0; m < 4; ++m)
            #pragma unroll
            for (int r = 0; r < 4; ++r) acc[n][m][r] = 0.0f;

    #pragma unroll
    for (int s = 0; s < 2; ++s) {
        if (s) __syncthreads();
        const int ks = s * 64;
        #pragma unroll
        for (int p = 0; p < 2; ++p) {
            int c   = t + 1024 * p;
            int row = c >> 3;          // 0..255
            int off = (c & 7) * 8;     // bf16 col, 0..56
            uint4 va = *(const uint4*)(qnb + (size_t)(R0 + row) * D + ks + off);
            uint4 vb = *(const uint4*)(qb  + (size_t)(C0 + row) * D + ks + off);
            *(uint4*)&SM[0][row][off] = va;
            *(uint4*)&SM[1][row][off] = vb;
        }
        __syncthreads();
        #pragma unroll
        for (int kk = 0; kk < 64; kk += 32) {
            int ko = kk + lg * 8;
            bf16x8 a[4], b[4];
            #pragma unroll
            for (int m = 0; m < 4; ++m)
                a[m] = *(const bf16x8*)&SM[0][wr * 64 + m * 16 + lc][ko];
            #pragma unroll
            for (int n = 0; n < 4; ++n)
                b[n] = *(const bf16x8*)&SM[1][wc * 64 + n * 16 + lc][ko];
            #pragma unroll
            for (int n = 0; n < 4; ++n)
                #pragma unroll
                for (int m = 0; m < 4; ++m)
                    acc[n][m] = __builtin_amdgcn_mfma_f32_16x16x32_bf16(b[n], a[m], acc[n][m], 0, 0, 0);
        }
    }

    // ---- epilogue: direct register->global float4 stores + fused fixed-ref
    //      sumexp (logits in [-5,5] -> M=5). No barriers, no LDS.
    const int slot = bx * 4 + wc;
    #pragma unroll
    for (int m = 0; m < 4; ++m) {
        const size_t rowBase = (size_t)(R0 + wr * 64 + m * 16 + lc) * Q + C0 + wc * 64;
        float e = 0.0f;
        #pragma unroll
        for (int n = 0; n < 4; ++n) {
            float v0 = acc[n][m][0] * TEMP_INV;
            float v1 = acc[n][m][1] * TEMP_INV;
            float v2 = acc[n][m][2] * TEMP_INV;
            float v3 = acc[n][m][3] * TEMP_INV;
            float4 o = make_float4(v0, v1, v2, v3);
            *(float4*)(neg + rowBase + n * 16 + lg * 4) = o;
            e += __expf(v0 - 5.0f) + __expf(v1 - 5.0f) +
                 __expf(v2 - 5.0f) + __expf(v3 - 5.0f);
        }
        e += __shfl_xor(e, 16);
        e += __shfl_xor(e, 32);
        if (lg == 0) {
            int gr = R0 + wr * 64 + m * 16 + lc;
            psum[(size_t)gr * NPART + slot] = e;
        }
    }
}

// --- K3: reduce 1024 partial sums per row + pos -> loss_b -----------------
__global__ __launch_bounds__(256) void k_reduce_lse(const float* __restrict__ psum,
                                                    const float* __restrict__ ws_pos,
                                                    float* __restrict__ loss_b) {
    int r = blockIdx.x;
    const float4* pr = (const float4*)(psum + (size_t)r * NPART);
    float4 v = pr[threadIdx.x];        // 256 threads x float4 = 1024 slots
    float s = v.x + v.y + v.z + v.w;
    s = wave_reduce_sum(s);
    __shared__ float sw[4];
    int w = threadIdx.x >> 6, lane = threadIdx.x & 63;
    if (lane == 0) sw[w] = s;
    __syncthreads();
    if (threadIdx.x == 0) {
        float S = sw[0] + sw[1] + sw[2] + sw[3];
        float pos = ws_pos[r];
        S += __expf(pos - 5.0f);
        loss_b[r] = (logf(S) + 5.0f) - pos;   // lse - pos
    }
}

// --- K4: mean of loss_b -> out[0] -----------------------------------------
__global__ void k_loss_mean(const float* __restrict__ loss_b, float* __restrict__ out) {
    float s = 0.0f;
    for (int i = threadIdx.x; i < B; i += 256) s += loss_b[i];
    s = wave_reduce_sum(s);
    __shared__ float sw[4];
    int w = threadIdx.x >> 6, lane = threadIdx.x & 63;
    if (lane == 0) sw[w] = s;
    __syncthreads();
    if (threadIdx.x == 0) out[0] = (sw[0] + sw[1] + sw[2] + sw[3]) / (float)B;
}

extern "C" void kernel_launch(void* const* d_in, const int* in_sizes, int n_in,
                              void* d_out, int out_size, void* d_ws, size_t ws_size,
                              hipStream_t stream) {
    const float* g1    = (const float*)d_in[0];
    const float* g2    = (const float*)d_in[1];
    const float* queue = (const float*)d_in[2];
    float* out = (float*)d_out;

    float* out_pos = out + 1;          // pos_sim [B]
    float* neg     = out + 1 + B;      // neg_sim [B][Q]

    // ws layout: qnb bf16[B*D] | qb bf16[Q*D] | psum f32[B*NPART]
    //            | ws_pos f32[B] | loss_b f32[B]
    unsigned short* qnb = (unsigned short*)d_ws;
    unsigned short* qb  = qnb + (size_t)B * D;
    float* psum   = (float*)(qb + (size_t)Q * D);
    float* ws_pos = psum + (size_t)B * NPART;
    float* loss_b = ws_pos + B;

    k_prep<<<Q / 8 + B / 2, 256, 0, stream>>>(g1, g2, queue, qnb, qb, out_pos, ws_pos);
    k_gemm_mfma<<<(Q / 256) * (B / 256), 1024, 0, stream>>>(qnb, qb, neg, psum);
    k_reduce_lse<<<B, 256, 0, stream>>>(psum, ws_pos, loss_b);
    k_loss_mean<<<1, 256, 0, stream>>>(loss_b, out);
}